// Round 4
// baseline (301.147 us; speedup 1.0000x reference)
//
#include <hip/hip_runtime.h>
#include <stdint.h>

// out[b,c] = sum_{k<256} batchs[b,k] * label2embed[c,k]
// A = batchs [16384, 256] fp32 row-major, Bm = label2embed [4096, 256] fp32 row-major
// out [16384, 4096] fp32. GEMM-BT, K=256. Output-write floor: 43.7 us (268 MB @ 6.3 TB/s).
//
// Session ledger:
//  R0: fill(~167, unconditional ws poison, fixed tax) + cvt(6) + gemm_bt(~120) = 297.
//  R1: cvt fused into gemm -> 50x VALU cvt blowup, gemm 186. REVERTED.
//  R2: no-LDS direct-from-L2 fragments -> gemm 206. REVERTED (global_load_lds staging wins).
//  R3: swapped-operand MFMA + f32x4 epilogue -> NEUTRAL (gemm not store-issue-bound).
//  R4 (this): gemm is stall-bound: per-step __syncthreads = vmcnt(0) drain of loads
//      issued only ~200cy earlier, 8x per block, all waves synchronized. Fix = T4-lite:
//      TRIPLE-buffered LDS, prefetch distance 2, raw s_barrier + counted s_waitcnt
//      vmcnt(4) (oldest step's loads only; 8 newer stay in flight across the barrier).
//      lgkmcnt(0) before barrier preserves the WAR guarantee on the recycled buffer.
#define MDIM 16384
#define NDIM 4096
#define KDIM 256

#define BM 128
#define BN 128
#define BK 32
#define KSTEPS (KDIM / BK)   // 8

typedef __attribute__((ext_vector_type(8))) short bf16x8;
typedef __attribute__((ext_vector_type(4))) float f32x4;

__device__ __forceinline__ unsigned short f2bf_rne(float f) {
    union { float f; uint32_t u; } v; v.f = f;
    uint32_t u = v.u;
    u += 0x7fffu + ((u >> 16) & 1u);   // round-to-nearest-even (finite inputs)
    return (unsigned short)(u >> 16);
}

// Pass 1: fp32 -> bf16 for both inputs, into workspace. 8 elems/thread, 16B stores.
__global__ __launch_bounds__(256) void cvt_kernel(const float* __restrict__ a,
                                                  const float* __restrict__ b,
                                                  unsigned short* __restrict__ wa,
                                                  unsigned short* __restrict__ wb) {
    const int64_t nA = (int64_t)MDIM * KDIM;
    int64_t i = ((int64_t)blockIdx.x * 256 + threadIdx.x) * 8;
    const float* src; unsigned short* dst; int64_t off;
    if (i < nA) { src = a; dst = wa; off = i; }
    else        { src = b; dst = wb; off = i - nA; }
    float4 f0 = *(const float4*)(src + off);
    float4 f1 = *(const float4*)(src + off + 4);
    union { unsigned short h[8]; int4 v; } o;
    o.h[0] = f2bf_rne(f0.x); o.h[1] = f2bf_rne(f0.y);
    o.h[2] = f2bf_rne(f0.z); o.h[3] = f2bf_rne(f0.w);
    o.h[4] = f2bf_rne(f1.x); o.h[5] = f2bf_rne(f1.y);
    o.h[6] = f2bf_rne(f1.z); o.h[7] = f2bf_rne(f1.w);
    *(int4*)(dst + off) = o.v;
}

// Stage one 128x32 bf16 tile of A and B into LDS via width-16 global_load_lds.
// chunk ch in [0,512): row = ch>>2, col = (ch&3)*8; LDS byte off = ch*16.
// Each thread issues exactly 4 loads (2 A + 2 B) -> vmcnt bookkeeping unit = 4.
__device__ __forceinline__ void stage_tiles(const unsigned short* __restrict__ Ab,
                                            const unsigned short* __restrict__ Bb,
                                            unsigned short* sA, unsigned short* sB,
                                            int tid, int k0) {
#pragma unroll
    for (int c = 0; c < 2; ++c) {
        int ch  = tid + c * 256;
        int row = ch >> 2;
        int col = (ch & 3) << 3;
        __builtin_amdgcn_global_load_lds(
            (const __attribute__((address_space(1))) void*)(Ab + (size_t)row * KDIM + k0 + col),
            (__attribute__((address_space(3))) void*)(sA + ch * 8), 16, 0, 0);
        __builtin_amdgcn_global_load_lds(
            (const __attribute__((address_space(1))) void*)(Bb + (size_t)row * KDIM + k0 + col),
            (__attribute__((address_space(3))) void*)(sB + ch * 8), 16, 0, 0);
    }
}

// Pass 2: bf16 MFMA GEMM-BT. 128x128 tile/block, 4 waves, each a 64x64 quadrant.
// TRIPLE-buffered LDS (48 KiB), prefetch distance 2, counted vmcnt:
//   prologue: stage(0), stage(1)                          -> 8 loads in flight
//   step s:   lgkmcnt(0)                                  -> my buf[s-1] reads done (WAR)
//             vmcnt(4) [vmcnt(0) at last step]            -> step-s loads landed,
//                                                            step-s+1's stay in flight
//             s_barrier                                   -> ALL waves' s-loads landed,
//                                                            all done reading buf[s-1]
//             stage(s+2) into buf[(s+2)%3]                -> safe: last read 2 barriers ago
//             ds_read frags from buf[s%3] + 16 MFMA
// Never drains vmcnt to 0 in the main loop (T4). 3 blocks/CU (LDS-capped), 12 waves/CU.
__global__ __launch_bounds__(256, 3) void gemm_bt(const unsigned short* __restrict__ A,
                                                  const unsigned short* __restrict__ Bm,
                                                  float* __restrict__ out) {
    __shared__ __align__(16) unsigned short sA[3][BM * BK];  // 3 x 8 KiB
    __shared__ __align__(16) unsigned short sB[3][BN * BK];  // 3 x 8 KiB

    const int tid  = threadIdx.x;
    const int lane = tid & 63;
    const int wave = tid >> 6;
    const int wm   = wave >> 1;
    const int wn   = wave & 1;
    const int quad = lane >> 4;
    const int r16  = lane & 15;

    // XCD-aware swizzle: xcd = blockIdx % 8. Each XCD owns a band of 16 bm's; bn sweeps
    // fastest -> per-XCD set = A band (1 MB) + full B (2 MB) = 3 MB < 4 MB XCD L2.
    const int id  = blockIdx.x;
    const int xcd = id & 7;
    const int g   = id >> 3;                // 0..511
    const int bm  = (xcd << 4) | (g >> 5);  // 0..127
    const int bn  = g & 31;                 // 0..31

    const unsigned short* Ab = A  + (size_t)bm * BM * KDIM;
    const unsigned short* Bb = Bm + (size_t)bn * BN * KDIM;

    f32x4 acc[4][4] = {};

    stage_tiles(Ab, Bb, sA[0], sB[0], tid, 0);
    stage_tiles(Ab, Bb, sA[1], sB[1], tid, BK);

#pragma unroll
    for (int step = 0; step < KSTEPS; ++step) {
        // WAR guarantee: my ds_reads of buf[step-1] complete before I pass the barrier.
        asm volatile("s_waitcnt lgkmcnt(0)" ::: "memory");
        // Counted wait: retire the oldest 4 loads (step s); keep the 4 newer in flight.
        if (step < KSTEPS - 1)
            asm volatile("s_waitcnt vmcnt(4)" ::: "memory");
        else
            asm volatile("s_waitcnt vmcnt(0)" ::: "memory");
        __builtin_amdgcn_s_barrier();
        asm volatile("" ::: "memory");   // fence: no LDS reads hoisted above the barrier

        if (step + 2 < KSTEPS)
            stage_tiles(Ab, Bb, sA[(step + 2) % 3], sB[(step + 2) % 3], tid, (step + 2) * BK);

        const unsigned short* cA = sA[step % 3];
        const unsigned short* cB = sB[step % 3];

        // Fragment: X[row = lane&15][k = quad*8 + j]  (one ds_read_b128 each)
        bf16x8 af[4], bfr[4];
#pragma unroll
        for (int i = 0; i < 4; ++i)
            af[i] = *(const bf16x8*)(cA + ((wm * 64 + i * 16 + r16) * BK + quad * 8));
#pragma unroll
        for (int j = 0; j < 4; ++j)
            bfr[j] = *(const bf16x8*)(cB + ((wn * 64 + j * 16 + r16) * BK + quad * 8));

        // SWAPPED operands (validated R1-R3): D = mfma(bfr, af) ->
        // D col-field (lane&15) = out row, D row-field (quad*4+reg) = out col.
#pragma unroll
        for (int i = 0; i < 4; ++i)
#pragma unroll
            for (int j = 0; j < 4; ++j)
                acc[i][j] = __builtin_amdgcn_mfma_f32_16x16x32_bf16(bfr[j], af[i], acc[i][j], 0, 0, 0);
    }

    // Epilogue: 16 dwordx4 stores/lane; per instruction 16 rows x 64B contiguous.
#pragma unroll
    for (int i = 0; i < 4; ++i) {
        size_t row = (size_t)bm * BM + wm * 64 + i * 16 + r16;
#pragma unroll
        for (int j = 0; j < 4; ++j) {
            int col = bn * BN + wn * 64 + j * 16 + quad * 4;
            *(f32x4*)(out + row * NDIM + col) = acc[i][j];
        }
    }
}

// Fallback (only if ws too small): fp32 dot, one thread per output.
__global__ __launch_bounds__(256) void naive_f32(const float* __restrict__ a,
                                                 const float* __restrict__ b,
                                                 float* __restrict__ out) {
    int64_t idx = (int64_t)blockIdx.x * 256 + threadIdx.x;
    int c = (int)(idx & (NDIM - 1));
    int r = (int)(idx >> 12);
    const float4* ap = (const float4*)(a + (size_t)r * KDIM);
    const float4* bp = (const float4*)(b + (size_t)c * KDIM);
    float s = 0.f;
#pragma unroll 8
    for (int k = 0; k < KDIM / 4; ++k) {
        float4 x = ap[k], y = bp[k];
        s += x.x * y.x + x.y * y.y + x.z * y.z + x.w * y.w;
    }
    out[idx] = s;
}

extern "C" void kernel_launch(void* const* d_in, const int* in_sizes, int n_in,
                              void* d_out, int out_size, void* d_ws, size_t ws_size,
                              hipStream_t stream) {
    const float* a = (const float*)d_in[0];   // batchs  [16384, 2, 128]
    const float* b = (const float*)d_in[1];   // label2embed [4096, 2, 128]
    float* out = (float*)d_out;               // [16384, 4096]

    const size_t need = ((size_t)MDIM + NDIM) * KDIM * sizeof(unsigned short); // 10.5 MB
    if (d_ws != nullptr && ws_size >= need) {
        unsigned short* wa = (unsigned short*)d_ws;
        unsigned short* wb = wa + (size_t)MDIM * KDIM;
        const int64_t nvec = ((int64_t)MDIM + NDIM) * KDIM / 8;  // 655,360
        cvt_kernel<<<(int)(nvec / 256), 256, 0, stream>>>(a, b, wa, wb);       // 2560 blocks
        gemm_bt<<<(MDIM / BM) * (NDIM / BN), 256, 0, stream>>>(wa, wb, out);   // 4096 blocks
    } else {
        naive_f32<<<(int64_t)MDIM * NDIM / 256, 256, 0, stream>>>(a, b, out);
    }
}